// Round 5
// baseline (1096.173 us; speedup 1.0000x reference)
//
#include <hip/hip_runtime.h>
#include <math.h>

#define NB   4096
#define LL   50
#define FF   128
#define HH   8
#define DVn  16

typedef __attribute__((ext_vector_type(8))) short bf16x8;
typedef __attribute__((ext_vector_type(4))) float f32x4;

__device__ __forceinline__ ushort bf_hi(float x) {
    uint u = __float_as_uint(x);
    uint r = u + 0x7FFFu + ((u >> 16) & 1u);   // RTNE to bf16
    return (ushort)(r >> 16);
}
__device__ __forceinline__ float bf_f(ushort b) { return __uint_as_float(((uint)b) << 16); }

// ---------------- pack: M = Wq Wk^T (A-frag), u = Wq bk, v = Wk bq, c = bq.bk, Wv ----
// v5 pack (kept): 80 blocks x 256 threads; Wq-tile + full Wk staged in LDS,
// identical e-order -> bit-identical M. Tiles 8/9 unchanged semantics.
__global__ __launch_bounds__(256)
void pack_w(const float* __restrict__ Wq, const float* __restrict__ bq,
            const float* __restrict__ Wk, const float* __restrict__ bk,
            const float* __restrict__ Wv, ushort* __restrict__ wp)
{
    __shared__ float sw[144*129];                  // 74304 B: wq 16x129, wk 128x129
    const int t    = threadIdx.x;
    const int lane = t & 63;
    const int ks   = t >> 6;
    const int h    = blockIdx.x / 10;
    const int tile = blockIdx.x % 10;
    const int c    = lane & 15;
    const int quad = lane >> 4;
    const int f0   = ks*32 + quad*8;

    float val[8];
    #pragma unroll
    for (int j = 0; j < 8; ++j) val[j] = 0.f;

    if (tile < 8) {                                // A-frag: M[16t+c][32ks+quad*8+j]
        const float* wq = Wq + (size_t)h*FF*FF;
        const float* wk = Wk + (size_t)h*FF*FF;
        float* wqs = sw;                           // 16 x 129
        float* wks = sw + 16*129;                  // 128 x 129 (all g rows)
        for (int i = t; i < 16*128; i += 256)
            wqs[(i>>7)*129 + (i&127)] = wq[(size_t)(tile*16 + (i>>7))*FF + (i&127)];
        for (int i = t; i < 128*128; i += 256)
            wks[(i>>7)*129 + (i&127)] = wk[i];
        __syncthreads();
        const int g0 = ks*32 + quad*8;
        for (int e = 0; e < FF; ++e) {             // identical order -> bit-identical M
            float qv = wqs[c*129 + e];
            #pragma unroll
            for (int j = 0; j < 8; ++j)
                val[j] += wks[(g0+j)*129 + e] * qv;
        }
    } else if (tile == 8) {                        // col0 = u = Wq bk, col1 = v = Wk bq
        const float* wq = Wq + (size_t)h*FF*FF;
        const float* wk = Wk + (size_t)h*FF*FF;
        float pu[8], pv[8];
        #pragma unroll
        for (int j = 0; j < 8; ++j) { pu[j] = 0.f; pv[j] = 0.f; }
        for (int ee = 0; ee < 8; ++ee) {           // lane c handles e in [8c, 8c+8)
            int e = c*8 + ee;
            float bkk = bk[h*FF + e], bqq = bq[h*FF + e];
            #pragma unroll
            for (int j = 0; j < 8; ++j) {
                pu[j] += wq[(size_t)(f0+j)*FF + e] * bkk;
                pv[j] += wk[(size_t)(f0+j)*FF + e] * bqq;
            }
        }
        #pragma unroll
        for (int m = 1; m < 16; m <<= 1) {         // reduce over c (quad preserved)
            #pragma unroll
            for (int j = 0; j < 8; ++j) {
                pu[j] += __shfl_xor(pu[j], m);
                pv[j] += __shfl_xor(pv[j], m);
            }
        }
        if (c == 0) {
            #pragma unroll
            for (int j = 0; j < 8; ++j) val[j] = pu[j];
        } else if (c == 1) {
            #pragma unroll
            for (int j = 0; j < 8; ++j) val[j] = pv[j];
        }
        if (ks == 0) {                             // c = bq.bk, wave-parallel
            float s = bq[h*FF + lane*2]*bk[h*FF + lane*2]
                    + bq[h*FF + lane*2 + 1]*bk[h*FF + lane*2 + 1];
            #pragma unroll
            for (int m = 1; m < 64; m <<= 1) s += __shfl_xor(s, m);
            if (lane == 0) ((float*)(wp + 327680))[h] = s;
        }
    } else {                                       // Wv B-frag
        const float* wv = Wv + (size_t)h*FF*DVn;
        #pragma unroll
        for (int j = 0; j < 8; ++j) val[j] = wv[(size_t)(f0+j)*DVn + c];
    }

    ushort hi[8], lo[8];
    #pragma unroll
    for (int j = 0; j < 8; ++j) {
        ushort hb = bf_hi(val[j]);
        hi[j] = hb;
        lo[j] = bf_hi(val[j] - bf_f(hb));
    }
    size_t base = (size_t)h*40960 + (size_t)tile*4096 + ks*1024 + lane*8;
    *(ushort4*)(wp + base)       = make_ushort4(hi[0],hi[1],hi[2],hi[3]);
    *(ushort4*)(wp + base + 4)   = make_ushort4(hi[4],hi[5],hi[6],hi[7]);
    *(ushort4*)(wp + base + 512) = make_ushort4(lo[0],lo[1],lo[2],lo[3]);
    *(ushort4*)(wp + base + 516) = make_ushort4(lo[4],lo[5],lo[6],lo[7]);
}

// ---------------- fused attention ----------------
// v6 = v5 with __launch_bounds__(256, 3): the (256,4) hard cap (128 unified regs)
//     made the allocator spill xh[16] to scratch (VGPR=52, FETCH 2.7 GB, 2.7x
//     regression). v5's structure needs ~100-110 unified regs (aG[4]=16 vs v4's
//     aT=32; one M-pair live vs two); under the relaxed 170 cap there is no
//     spill, and since natural usage <= 128 the HW reaches 4 blocks/CU anyway
//     (LDS 35328 B allows 4). Graceful degradation to 3 blocks if allocator
//     lands above 128 -- instead of catastrophic spill.
// LDS (ushorts; 35328 B):
//   xl panels [mt4][ks4] @0 (persist, stride 512)
//   x-hi staging @8192 (dead after reg preload) == G-hi half (8 panels) @8192,
//   G-lo half @12288; satt bf16 [64][88] @8192 (overlay G, barrier-separated)
//   vf @16384 (2 ks panels x 512); tu[64],tv[64] fp32 @float 8704/8768
#define XL0   0
#define XH0   8192
#define GH0   8192
#define GLD   4096
#define SATT0 8192
#define SATTP 88
#define VF0   16384
#define TU0   8704
#define TV0   8768
#define LDS_FLOATS 8832

__global__ __launch_bounds__(256, 3)
void attn_fused(const float* __restrict__ hid, const ushort* __restrict__ wp,
                const float* __restrict__ ccp, const float* __restrict__ bv,
                float* __restrict__ out)
{
    __shared__ __align__(16) float lds[LDS_FLOATS];
    ushort* us = (ushort*)lds;
    float*  tu = lds + TU0;
    float*  tv = lds + TV0;

    const int t    = threadIdx.x;
    const int b    = blockIdx.x;
    const int lane = t & 63;
    const int w    = t >> 6;
    const int c16  = lane & 15;
    const int quad = lane >> 4;

    // ---- stage x -> bf16 hi/lo A-frag panels, ONCE per b (trunc split; rows >= 50
    //      garbage, masked later) ----
    {
        const float4* src = (const float4*)(hid + (size_t)b * (LL*FF));
        for (int i = t; i < 1600; i += 256) {
            float4 v = src[i];
            int l = i >> 5, f0 = (i & 31) * 4;
            int slot = ((l>>4)*4 + (f0>>5))*512 + ((l&15) + 16*((f0&31)>>3))*8 + (f0&7);
            ushort4 hv, lv;
            uint ux;
            ux = __float_as_uint(v.x); hv.x = (ushort)(ux>>16);
            lv.x = (ushort)(__float_as_uint(v.x - __uint_as_float(ux & 0xFFFF0000u))>>16);
            ux = __float_as_uint(v.y); hv.y = (ushort)(ux>>16);
            lv.y = (ushort)(__float_as_uint(v.y - __uint_as_float(ux & 0xFFFF0000u))>>16);
            ux = __float_as_uint(v.z); hv.z = (ushort)(ux>>16);
            lv.z = (ushort)(__float_as_uint(v.z - __uint_as_float(ux & 0xFFFF0000u))>>16);
            ux = __float_as_uint(v.w); hv.w = (ushort)(ux>>16);
            lv.w = (ushort)(__float_as_uint(v.w - __uint_as_float(ux & 0xFFFF0000u))>>16);
            *(ushort4*)(us + XH0 + slot) = hv;
            *(ushort4*)(us + XL0 + slot) = lv;
        }
    }
    __syncthreads();

    // ---- preload ALL 16 x-hi frags into registers (staging region becomes G) ----
    bf16x8 xh[16];
    #pragma unroll
    for (int i = 0; i < 16; ++i)
        xh[i] = *(const bf16x8*)(us + XH0 + i*512 + lane*8);
    __syncthreads();

    #pragma unroll 1
    for (int h = 0; h < HH; ++h) {
        const ushort* wb = wp + (size_t)h*40960 + lane*8;
        #define WFRG(tt,kk,pp) (*(const bf16x8*)(wb + (size_t)(tt)*4096 + (kk)*1024 + (pp)*512))

        f32x4 sc[4], aU, aV;
        #pragma unroll
        for (int m = 0; m < 4; ++m) sc[m] = (f32x4){0.f,0.f,0.f,0.f};
        aU = (f32x4){0.f,0.f,0.f,0.f};
        aV = (f32x4){0.f,0.f,0.f,0.f};

        #pragma unroll
        for (int hf = 0; hf < 2; ++hf) {
            // ---- G-half = M.x^T for f-tile ft = 4hf + w (all g-spans) ----
            f32x4 aG[4];
            #pragma unroll
            for (int m = 0; m < 4; ++m) aG[m] = (f32x4){0.f,0.f,0.f,0.f};
            const int ft = 4*hf + w;

            #pragma unroll
            for (int ksg = 0; ksg < 4; ++ksg) {
                bf16x8 mh = WFRG(ft, ksg, 0), ml = WFRG(ft, ksg, 1);
                #pragma unroll
                for (int mt = 0; mt < 4; ++mt) {
                    bf16x8 bh = xh[mt*4 + ksg];
                    bf16x8 bl = *(const bf16x8*)(us + XL0 + (mt*4 + ksg)*512 + lane*8);
                    aG[mt] = __builtin_amdgcn_mfma_f32_16x16x32_bf16(mh, bh, aG[mt], 0,0,0);
                    aG[mt] = __builtin_amdgcn_mfma_f32_16x16x32_bf16(ml, bh, aG[mt], 0,0,0);
                    aG[mt] = __builtin_amdgcn_mfma_f32_16x16x32_bf16(mh, bl, aG[mt], 0,0,0);
                }
            }
            // ---- U/V for this half's f-blocks (accumulate across halves) ----
            #pragma unroll
            for (int kb = 0; kb < 2; ++kb) {
                const int ksf = 2*hf + kb;
                bf16x8 uvh = WFRG(8, ksf, 0), vvh = WFRG(9, ksf, 0);
                bf16x8 bhx = xh[w*4 + ksf];
                bf16x8 blx = *(const bf16x8*)(us + XL0 + (w*4 + ksf)*512 + lane*8);
                aU = __builtin_amdgcn_mfma_f32_16x16x32_bf16(bhx, uvh, aU, 0,0,0);
                aV = __builtin_amdgcn_mfma_f32_16x16x32_bf16(bhx, vvh, aV, 0,0,0);
                aV = __builtin_amdgcn_mfma_f32_16x16x32_bf16(blx, vvh, aV, 0,0,0);
            }

            // ---- epilogue-half: G C-frag -> B-frag panels (contiguous b64) ----
            // f = 16ft + quad*4 + r; panel p = mt*2 + (w>>1);
            // grp = c16 + 16*(2*(w&1) + (quad>>1)), j = (quad&1)*4 + r
            {
                const int pkb  = w >> 1;
                const int grp  = c16 + 16*(2*(w&1) + (quad>>1));
                const int joff = (quad&1)*4;
                #pragma unroll
                for (int mt = 0; mt < 4; ++mt) {
                    uint u0 = __float_as_uint(aG[mt][0]);
                    uint u1 = __float_as_uint(aG[mt][1]);
                    uint u2 = __float_as_uint(aG[mt][2]);
                    uint u3 = __float_as_uint(aG[mt][3]);
                    uint hw0 = (u0>>16) | (u1 & 0xFFFF0000u);
                    uint hw1 = (u2>>16) | (u3 & 0xFFFF0000u);
                    float l0 = aG[mt][0] - __uint_as_float(u0 & 0xFFFF0000u);
                    float l1 = aG[mt][1] - __uint_as_float(u1 & 0xFFFF0000u);
                    float l2 = aG[mt][2] - __uint_as_float(u2 & 0xFFFF0000u);
                    float l3 = aG[mt][3] - __uint_as_float(u3 & 0xFFFF0000u);
                    uint lw0 = (__float_as_uint(l0)>>16) | (__float_as_uint(l1) & 0xFFFF0000u);
                    uint lw1 = (__float_as_uint(l2)>>16) | (__float_as_uint(l3) & 0xFFFF0000u);
                    ushort* dst = us + GH0 + (mt*2 + pkb)*512 + grp*8 + joff;
                    *(uint2*)dst         = make_uint2(hw0, hw1);
                    *(uint2*)(dst + GLD) = make_uint2(lw0, lw1);
                }
                if (hf == 1) {                      // aU/aV complete -> tu/tv/vf
                    if (c16 < 2) {
                        float* dst = (c16 == 0) ? tu : tv;
                        #pragma unroll
                        for (int r = 0; r < 4; ++r) dst[w*16 + quad*4 + r] = aU[r];
                    }
                    float bvv = bv[h*DVn + c16];
                    int ksp = w >> 1;
                    #pragma unroll
                    for (int r = 0; r < 4; ++r) {
                        int m  = w*16 + quad*4 + r;
                        int mm = (w&1)*16 + quad*4 + r;
                        int Lp = c16 + 16*(mm >> 3);
                        us[VF0 + ksp*512 + Lp*8 + (mm & 7)] = (m < LL) ? bf_hi(aV[r] + bvv)
                                                                       : (ushort)0;
                    }
                }
            }
            __syncthreads();                        // G-half (+tu/tv/vf) visible

            // ---- scores-half: S += x.G over ks = 2hf..2hf+1. Wave w: col-tile w ----
            #pragma unroll
            for (int kb = 0; kb < 2; ++kb) {
                const int ks = 2*hf + kb;
                const ushort* gb = us + GH0 + (w*2 + kb)*512 + lane*8;
                bf16x8 gh = *(const bf16x8*)gb;
                bf16x8 gl = *(const bf16x8*)(gb + GLD);
                #pragma unroll
                for (int mt = 0; mt < 4; ++mt) {
                    bf16x8 ah = xh[mt*4 + ks];
                    bf16x8 al = *(const bf16x8*)(us + XL0 + (mt*4 + ks)*512 + lane*8);
                    sc[mt] = __builtin_amdgcn_mfma_f32_16x16x32_bf16(ah, gh, sc[mt], 0,0,0);
                    sc[mt] = __builtin_amdgcn_mfma_f32_16x16x32_bf16(al, gh, sc[mt], 0,0,0);
                    sc[mt] = __builtin_amdgcn_mfma_f32_16x16x32_bf16(ah, gl, sc[mt], 0,0,0);
                }
            }
            __syncthreads();                        // G reads done (next half / satt overwrite)
        }

        // ---- rank-1/const terms, leaky, column softmax (tu via float4) ----
        const float cc  = ccp[h];
        const int mcol  = w*16 + c16;
        const float tvv = tv[mcol] + cc;
        float mx = -INFINITY;
        #pragma unroll
        for (int mt = 0; mt < 4; ++mt) {
            const float4 tq = *(const float4*)(tu + mt*16 + quad*4);
            float tqa[4] = {tq.x, tq.y, tq.z, tq.w};
            #pragma unroll
            for (int r = 0; r < 4; ++r) {
                int l = mt*16 + quad*4 + r;
                float s = sc[mt][r] + tqa[r] + tvv;
                s = (s > 0.f) ? s : 0.1f*s;
                sc[mt][r] = s;
                if (l < LL) mx = fmaxf(mx, s);
            }
        }
        mx = fmaxf(mx, __shfl_xor(mx, 16));
        mx = fmaxf(mx, __shfl_xor(mx, 32));
        float sum = 0.f;
        #pragma unroll
        for (int mt = 0; mt < 4; ++mt)
            #pragma unroll
            for (int r = 0; r < 4; ++r) {
                int l = mt*16 + quad*4 + r;
                float p = (l < LL) ? __expf(sc[mt][r] - mx) : 0.f;
                sc[mt][r] = p;
                sum += p;
            }
        sum += __shfl_xor(sum, 16);
        sum += __shfl_xor(sum, 32);
        float inv = 1.0f / sum;

        // satt bf16 [64][88] overlaid on G region; cols >=50 zeroed
        #pragma unroll
        for (int mt = 0; mt < 4; ++mt)
            #pragma unroll
            for (int r = 0; r < 4; ++r) {
                int l = mt*16 + quad*4 + r;
                us[SATT0 + l*SATTP + mcol] = (mcol < LL) ? bf_hi(sc[mt][r] * inv) : (ushort)0;
            }
        __syncthreads();                            // satt visible

        // ---- out = relu(att.V) via MFMA; wave w owns l-tile w ----
        f32x4 ao = (f32x4){0.f,0.f,0.f,0.f};
        #pragma unroll
        for (int ksp = 0; ksp < 2; ++ksp) {
            bf16x8 af = *(const bf16x8*)(us + SATT0 + (w*16 + c16)*SATTP + ksp*32 + quad*8);
            bf16x8 bf = *(const bf16x8*)(us + VF0 + ksp*512 + lane*8);
            ao = __builtin_amdgcn_mfma_f32_16x16x32_bf16(af, bf, ao, 0,0,0);
        }
        #pragma unroll
        for (int r = 0; r < 4; ++r) {
            int l = w*16 + quad*4 + r;
            if (l < LL)
                out[(size_t)b*(LL*FF) + l*FF + h*DVn + c16] = fmaxf(ao[r], 0.f);
        }
        __syncthreads();                            // protect satt/vf/tu/tv/G for next h
    }
}

extern "C" void kernel_launch(void* const* d_in, const int* in_sizes, int n_in,
                              void* d_out, int out_size, void* d_ws, size_t ws_size,
                              hipStream_t stream)
{
    const float* hid = (const float*)d_in[0];
    const float* Wq  = (const float*)d_in[1];
    const float* bq  = (const float*)d_in[2];
    const float* Wk  = (const float*)d_in[3];
    const float* bk  = (const float*)d_in[4];
    const float* Wv  = (const float*)d_in[5];
    const float* bv  = (const float*)d_in[6];
    float* o    = (float*)d_out;
    ushort* wp  = (ushort*)d_ws;                       // 655392 B used
    const float* ccp = (const float*)(wp + 327680);

    pack_w<<<dim3(80), dim3(256), 0, stream>>>(Wq, bq, Wk, bk, Wv, wp);
    attn_fused<<<dim3(NB), dim3(256), 0, stream>>>(hid, wp, ccp, bv, o);
}

// Round 6
// 498.220 us; speedup vs baseline: 2.2002x; 2.2002x over previous
//
#include <hip/hip_runtime.h>
#include <math.h>

#define NB   4096
#define LL   50
#define FF   128
#define HH   8
#define DVn  16

typedef __attribute__((ext_vector_type(8))) short bf16x8;
typedef __attribute__((ext_vector_type(4))) float f32x4;

__device__ __forceinline__ ushort bf_hi(float x) {
    uint u = __float_as_uint(x);
    uint r = u + 0x7FFFu + ((u >> 16) & 1u);   // RTNE to bf16
    return (ushort)(r >> 16);
}
__device__ __forceinline__ float bf_f(ushort b) { return __uint_as_float(((uint)b) << 16); }

// ---------------- pack: M = Wq Wk^T (A-frag), u = Wq bk, v = Wk bq, c = bq.bk, Wv ----
// v5 pack (kept): 80 blocks x 256 threads; Wq-tile + full Wk staged in LDS,
// identical e-order -> bit-identical M. Tiles 8/9 unchanged semantics.
__global__ __launch_bounds__(256)
void pack_w(const float* __restrict__ Wq, const float* __restrict__ bq,
            const float* __restrict__ Wk, const float* __restrict__ bk,
            const float* __restrict__ Wv, ushort* __restrict__ wp)
{
    __shared__ float sw[144*129];                  // 74304 B: wq 16x129, wk 128x129
    const int t    = threadIdx.x;
    const int lane = t & 63;
    const int ks   = t >> 6;
    const int h    = blockIdx.x / 10;
    const int tile = blockIdx.x % 10;
    const int c    = lane & 15;
    const int quad = lane >> 4;
    const int f0   = ks*32 + quad*8;

    float val[8];
    #pragma unroll
    for (int j = 0; j < 8; ++j) val[j] = 0.f;

    if (tile < 8) {                                // A-frag: M[16t+c][32ks+quad*8+j]
        const float* wq = Wq + (size_t)h*FF*FF;
        const float* wk = Wk + (size_t)h*FF*FF;
        float* wqs = sw;                           // 16 x 129
        float* wks = sw + 16*129;                  // 128 x 129 (all g rows)
        for (int i = t; i < 16*128; i += 256)
            wqs[(i>>7)*129 + (i&127)] = wq[(size_t)(tile*16 + (i>>7))*FF + (i&127)];
        for (int i = t; i < 128*128; i += 256)
            wks[(i>>7)*129 + (i&127)] = wk[i];
        __syncthreads();
        const int g0 = ks*32 + quad*8;
        for (int e = 0; e < FF; ++e) {             // identical order -> bit-identical M
            float qv = wqs[c*129 + e];
            #pragma unroll
            for (int j = 0; j < 8; ++j)
                val[j] += wks[(g0+j)*129 + e] * qv;
        }
    } else if (tile == 8) {                        // col0 = u = Wq bk, col1 = v = Wk bq
        const float* wq = Wq + (size_t)h*FF*FF;
        const float* wk = Wk + (size_t)h*FF*FF;
        float pu[8], pv[8];
        #pragma unroll
        for (int j = 0; j < 8; ++j) { pu[j] = 0.f; pv[j] = 0.f; }
        for (int ee = 0; ee < 8; ++ee) {           // lane c handles e in [8c, 8c+8)
            int e = c*8 + ee;
            float bkk = bk[h*FF + e], bqq = bq[h*FF + e];
            #pragma unroll
            for (int j = 0; j < 8; ++j) {
                pu[j] += wq[(size_t)(f0+j)*FF + e] * bkk;
                pv[j] += wk[(size_t)(f0+j)*FF + e] * bqq;
            }
        }
        #pragma unroll
        for (int m = 1; m < 16; m <<= 1) {         // reduce over c (quad preserved)
            #pragma unroll
            for (int j = 0; j < 8; ++j) {
                pu[j] += __shfl_xor(pu[j], m);
                pv[j] += __shfl_xor(pv[j], m);
            }
        }
        if (c == 0) {
            #pragma unroll
            for (int j = 0; j < 8; ++j) val[j] = pu[j];
        } else if (c == 1) {
            #pragma unroll
            for (int j = 0; j < 8; ++j) val[j] = pv[j];
        }
        if (ks == 0) {                             // c = bq.bk, wave-parallel
            float s = bq[h*FF + lane*2]*bk[h*FF + lane*2]
                    + bq[h*FF + lane*2 + 1]*bk[h*FF + lane*2 + 1];
            #pragma unroll
            for (int m = 1; m < 64; m <<= 1) s += __shfl_xor(s, m);
            if (lane == 0) ((float*)(wp + 327680))[h] = s;
        }
    } else {                                       // Wv B-frag
        const float* wv = Wv + (size_t)h*FF*DVn;
        #pragma unroll
        for (int j = 0; j < 8; ++j) val[j] = wv[(size_t)(f0+j)*DVn + c];
    }

    ushort hi[8], lo[8];
    #pragma unroll
    for (int j = 0; j < 8; ++j) {
        ushort hb = bf_hi(val[j]);
        hi[j] = hb;
        lo[j] = bf_hi(val[j] - bf_f(hb));
    }
    size_t base = (size_t)h*40960 + (size_t)tile*4096 + ks*1024 + lane*8;
    *(ushort4*)(wp + base)       = make_ushort4(hi[0],hi[1],hi[2],hi[3]);
    *(ushort4*)(wp + base + 4)   = make_ushort4(hi[4],hi[5],hi[6],hi[7]);
    *(ushort4*)(wp + base + 512) = make_ushort4(lo[0],lo[1],lo[2],lo[3]);
    *(ushort4*)(wp + base + 516) = make_ushort4(lo[4],lo[5],lo[6],lo[7]);
}

// ---------------- fused attention ----------------
// v7 = v5 with the rule-#20 fix: v5's U/V phase read xh[w*4+ksf] with RUNTIME w,
//     which forced the whole xh[16] array into scratch (VGPR=52, FETCH 2.7 GB --
//     the true root cause; (256,4) was incidental). Fixed via the v4 idiom:
//     compile-time cw loop + wave-uniform predicate, xh[cw*4+ksf] static.
//     Launch bounds (256,3): 170-reg budget (no spill); if natural usage <=128
//     the HW reaches 4 blocks/CU anyway (LDS 35328 B allows 4).
// LDS (ushorts; 35328 B):
//   xl panels [mt4][ks4] @0 (persist, stride 512)
//   x-hi staging @8192 (dead after reg preload) == G-hi half (8 panels) @8192,
//   G-lo half @12288; satt bf16 [64][88] @8192 (overlay G, barrier-separated)
//   vf @16384 (2 ks panels x 512); tu[64],tv[64] fp32 @float 8704/8768
#define XL0   0
#define XH0   8192
#define GH0   8192
#define GLD   4096
#define SATT0 8192
#define SATTP 88
#define VF0   16384
#define TU0   8704
#define TV0   8768
#define LDS_FLOATS 8832

__global__ __launch_bounds__(256, 3)
void attn_fused(const float* __restrict__ hid, const ushort* __restrict__ wp,
                const float* __restrict__ ccp, const float* __restrict__ bv,
                float* __restrict__ out)
{
    __shared__ __align__(16) float lds[LDS_FLOATS];
    ushort* us = (ushort*)lds;
    float*  tu = lds + TU0;
    float*  tv = lds + TV0;

    const int t    = threadIdx.x;
    const int b    = blockIdx.x;
    const int lane = t & 63;
    const int w    = t >> 6;
    const int c16  = lane & 15;
    const int quad = lane >> 4;

    // ---- stage x -> bf16 hi/lo A-frag panels, ONCE per b (trunc split; rows >= 50
    //      garbage, masked later) ----
    {
        const float4* src = (const float4*)(hid + (size_t)b * (LL*FF));
        for (int i = t; i < 1600; i += 256) {
            float4 v = src[i];
            int l = i >> 5, f0 = (i & 31) * 4;
            int slot = ((l>>4)*4 + (f0>>5))*512 + ((l&15) + 16*((f0&31)>>3))*8 + (f0&7);
            ushort4 hv, lv;
            uint ux;
            ux = __float_as_uint(v.x); hv.x = (ushort)(ux>>16);
            lv.x = (ushort)(__float_as_uint(v.x - __uint_as_float(ux & 0xFFFF0000u))>>16);
            ux = __float_as_uint(v.y); hv.y = (ushort)(ux>>16);
            lv.y = (ushort)(__float_as_uint(v.y - __uint_as_float(ux & 0xFFFF0000u))>>16);
            ux = __float_as_uint(v.z); hv.z = (ushort)(ux>>16);
            lv.z = (ushort)(__float_as_uint(v.z - __uint_as_float(ux & 0xFFFF0000u))>>16);
            ux = __float_as_uint(v.w); hv.w = (ushort)(ux>>16);
            lv.w = (ushort)(__float_as_uint(v.w - __uint_as_float(ux & 0xFFFF0000u))>>16);
            *(ushort4*)(us + XH0 + slot) = hv;
            *(ushort4*)(us + XL0 + slot) = lv;
        }
    }
    __syncthreads();

    // ---- preload ALL 16 x-hi frags into registers (staging region becomes G) ----
    bf16x8 xh[16];
    #pragma unroll
    for (int i = 0; i < 16; ++i)
        xh[i] = *(const bf16x8*)(us + XH0 + i*512 + lane*8);
    __syncthreads();

    #pragma unroll 1
    for (int h = 0; h < HH; ++h) {
        const ushort* wb = wp + (size_t)h*40960 + lane*8;
        #define WFRG(tt,kk,pp) (*(const bf16x8*)(wb + (size_t)(tt)*4096 + (kk)*1024 + (pp)*512))

        f32x4 sc[4], aU, aV;
        #pragma unroll
        for (int m = 0; m < 4; ++m) sc[m] = (f32x4){0.f,0.f,0.f,0.f};
        aU = (f32x4){0.f,0.f,0.f,0.f};
        aV = (f32x4){0.f,0.f,0.f,0.f};

        #pragma unroll
        for (int hf = 0; hf < 2; ++hf) {
            // ---- G-half = M.x^T for f-tile ft = 4hf + w (all g-spans) ----
            f32x4 aG[4];
            #pragma unroll
            for (int m = 0; m < 4; ++m) aG[m] = (f32x4){0.f,0.f,0.f,0.f};
            const int ft = 4*hf + w;

            #pragma unroll
            for (int ksg = 0; ksg < 4; ++ksg) {
                bf16x8 mh = WFRG(ft, ksg, 0), ml = WFRG(ft, ksg, 1);
                #pragma unroll
                for (int mt = 0; mt < 4; ++mt) {
                    bf16x8 bh = xh[mt*4 + ksg];                  // static index
                    bf16x8 bl = *(const bf16x8*)(us + XL0 + (mt*4 + ksg)*512 + lane*8);
                    aG[mt] = __builtin_amdgcn_mfma_f32_16x16x32_bf16(mh, bh, aG[mt], 0,0,0);
                    aG[mt] = __builtin_amdgcn_mfma_f32_16x16x32_bf16(ml, bh, aG[mt], 0,0,0);
                    aG[mt] = __builtin_amdgcn_mfma_f32_16x16x32_bf16(mh, bl, aG[mt], 0,0,0);
                }
            }
            // ---- U/V for this half's f-blocks: STATIC xh index via cw branch ----
            #pragma unroll
            for (int kb = 0; kb < 2; ++kb) {
                const int ksf = 2*hf + kb;
                bf16x8 uvh = WFRG(8, ksf, 0), vvh = WFRG(9, ksf, 0);
                bf16x8 blx = *(const bf16x8*)(us + XL0 + (w*4 + ksf)*512 + lane*8);
                #pragma unroll
                for (int cw = 0; cw < 4; ++cw) if (w == cw) {    // rule #20: static idx
                    bf16x8 bhx = xh[cw*4 + ksf];
                    aU = __builtin_amdgcn_mfma_f32_16x16x32_bf16(bhx, uvh, aU, 0,0,0);
                    aV = __builtin_amdgcn_mfma_f32_16x16x32_bf16(bhx, vvh, aV, 0,0,0);
                    aV = __builtin_amdgcn_mfma_f32_16x16x32_bf16(blx, vvh, aV, 0,0,0);
                }
            }

            // ---- epilogue-half: G C-frag -> B-frag panels (contiguous b64) ----
            // f = 16ft + quad*4 + r; panel p = mt*2 + (w>>1);
            // grp = c16 + 16*(2*(w&1) + (quad>>1)), j = (quad&1)*4 + r
            {
                const int pkb  = w >> 1;
                const int grp  = c16 + 16*(2*(w&1) + (quad>>1));
                const int joff = (quad&1)*4;
                #pragma unroll
                for (int mt = 0; mt < 4; ++mt) {
                    uint u0 = __float_as_uint(aG[mt][0]);
                    uint u1 = __float_as_uint(aG[mt][1]);
                    uint u2 = __float_as_uint(aG[mt][2]);
                    uint u3 = __float_as_uint(aG[mt][3]);
                    uint hw0 = (u0>>16) | (u1 & 0xFFFF0000u);
                    uint hw1 = (u2>>16) | (u3 & 0xFFFF0000u);
                    float l0 = aG[mt][0] - __uint_as_float(u0 & 0xFFFF0000u);
                    float l1 = aG[mt][1] - __uint_as_float(u1 & 0xFFFF0000u);
                    float l2 = aG[mt][2] - __uint_as_float(u2 & 0xFFFF0000u);
                    float l3 = aG[mt][3] - __uint_as_float(u3 & 0xFFFF0000u);
                    uint lw0 = (__float_as_uint(l0)>>16) | (__float_as_uint(l1) & 0xFFFF0000u);
                    uint lw1 = (__float_as_uint(l2)>>16) | (__float_as_uint(l3) & 0xFFFF0000u);
                    ushort* dst = us + GH0 + (mt*2 + pkb)*512 + grp*8 + joff;
                    *(uint2*)dst         = make_uint2(hw0, hw1);
                    *(uint2*)(dst + GLD) = make_uint2(lw0, lw1);
                }
                if (hf == 1) {                      // aU/aV complete -> tu/tv/vf
                    if (c16 < 2) {
                        float* dst = (c16 == 0) ? tu : tv;
                        #pragma unroll
                        for (int r = 0; r < 4; ++r) dst[w*16 + quad*4 + r] = aU[r];
                    }
                    float bvv = bv[h*DVn + c16];
                    int ksp = w >> 1;
                    #pragma unroll
                    for (int r = 0; r < 4; ++r) {
                        int m  = w*16 + quad*4 + r;
                        int mm = (w&1)*16 + quad*4 + r;
                        int Lp = c16 + 16*(mm >> 3);
                        us[VF0 + ksp*512 + Lp*8 + (mm & 7)] = (m < LL) ? bf_hi(aV[r] + bvv)
                                                                       : (ushort)0;
                    }
                }
            }
            __syncthreads();                        // G-half (+tu/tv/vf) visible

            // ---- scores-half: S += x.G over ks = 2hf..2hf+1. Wave w: col-tile w ----
            #pragma unroll
            for (int kb = 0; kb < 2; ++kb) {
                const int ks = 2*hf + kb;
                const ushort* gb = us + GH0 + (w*2 + kb)*512 + lane*8;
                bf16x8 gh = *(const bf16x8*)gb;
                bf16x8 gl = *(const bf16x8*)(gb + GLD);
                #pragma unroll
                for (int mt = 0; mt < 4; ++mt) {
                    bf16x8 ah = xh[mt*4 + ks];                   // static index
                    bf16x8 al = *(const bf16x8*)(us + XL0 + (mt*4 + ks)*512 + lane*8);
                    sc[mt] = __builtin_amdgcn_mfma_f32_16x16x32_bf16(ah, gh, sc[mt], 0,0,0);
                    sc[mt] = __builtin_amdgcn_mfma_f32_16x16x32_bf16(al, gh, sc[mt], 0,0,0);
                    sc[mt] = __builtin_amdgcn_mfma_f32_16x16x32_bf16(ah, gl, sc[mt], 0,0,0);
                }
            }
            __syncthreads();                        // G reads done (next half / satt overwrite)
        }

        // ---- rank-1/const terms, leaky, column softmax (tu via float4) ----
        const float cc  = ccp[h];
        const int mcol  = w*16 + c16;
        const float tvv = tv[mcol] + cc;
        float mx = -INFINITY;
        #pragma unroll
        for (int mt = 0; mt < 4; ++mt) {
            const float4 tq = *(const float4*)(tu + mt*16 + quad*4);
            float tqa[4] = {tq.x, tq.y, tq.z, tq.w};
            #pragma unroll
            for (int r = 0; r < 4; ++r) {
                int l = mt*16 + quad*4 + r;
                float s = sc[mt][r] + tqa[r] + tvv;
                s = (s > 0.f) ? s : 0.1f*s;
                sc[mt][r] = s;
                if (l < LL) mx = fmaxf(mx, s);
            }
        }
        mx = fmaxf(mx, __shfl_xor(mx, 16));
        mx = fmaxf(mx, __shfl_xor(mx, 32));
        float sum = 0.f;
        #pragma unroll
        for (int mt = 0; mt < 4; ++mt)
            #pragma unroll
            for (int r = 0; r < 4; ++r) {
                int l = mt*16 + quad*4 + r;
                float p = (l < LL) ? __expf(sc[mt][r] - mx) : 0.f;
                sc[mt][r] = p;
                sum += p;
            }
        sum += __shfl_xor(sum, 16);
        sum += __shfl_xor(sum, 32);
        float inv = 1.0f / sum;

        // satt bf16 [64][88] overlaid on G region; cols >=50 zeroed
        #pragma unroll
        for (int mt = 0; mt < 4; ++mt)
            #pragma unroll
            for (int r = 0; r < 4; ++r) {
                int l = mt*16 + quad*4 + r;
                us[SATT0 + l*SATTP + mcol] = (mcol < LL) ? bf_hi(sc[mt][r] * inv) : (ushort)0;
            }
        __syncthreads();                            // satt visible

        // ---- out = relu(att.V) via MFMA; wave w owns l-tile w ----
        f32x4 ao = (f32x4){0.f,0.f,0.f,0.f};
        #pragma unroll
        for (int ksp = 0; ksp < 2; ++ksp) {
            bf16x8 af = *(const bf16x8*)(us + SATT0 + (w*16 + c16)*SATTP + ksp*32 + quad*8);
            bf16x8 bf = *(const bf16x8*)(us + VF0 + ksp*512 + lane*8);
            ao = __builtin_amdgcn_mfma_f32_16x16x32_bf16(af, bf, ao, 0,0,0);
        }
        #pragma unroll
        for (int r = 0; r < 4; ++r) {
            int l = w*16 + quad*4 + r;
            if (l < LL)
                out[(size_t)b*(LL*FF) + l*FF + h*DVn + c16] = fmaxf(ao[r], 0.f);
        }
        __syncthreads();                            // protect satt/vf/tu/tv/G for next h
    }
}

extern "C" void kernel_launch(void* const* d_in, const int* in_sizes, int n_in,
                              void* d_out, int out_size, void* d_ws, size_t ws_size,
                              hipStream_t stream)
{
    const float* hid = (const float*)d_in[0];
    const float* Wq  = (const float*)d_in[1];
    const float* bq  = (const float*)d_in[2];
    const float* Wk  = (const float*)d_in[3];
    const float* bk  = (const float*)d_in[4];
    const float* Wv  = (const float*)d_in[5];
    const float* bv  = (const float*)d_in[6];
    float* o    = (float*)d_out;
    ushort* wp  = (ushort*)d_ws;                       // 655392 B used
    const float* ccp = (const float*)(wp + 327680);

    pack_w<<<dim3(80), dim3(256), 0, stream>>>(Wq, bq, Wk, bk, Wv, wp);
    attn_fused<<<dim3(NB), dim3(256), 0, stream>>>(hid, wp, ccp, bv, o);
}